// Round 2
// baseline (263.380 us; speedup 1.0000x reference)
//
#include <hip/hip_runtime.h>
#include <math.h>

#define NN 5000
#define NBINS 50
#define BINSZ 100
#define KNN 16
#define BPAD 104          // padded M row length (halves); 208 B stride, 16B aligned
#define MROWS 112         // padded row count in conv phase
#define NB 20             // nodes per block in MLP phases (5 groups x 4)
#define NBLK 250

typedef _Float16 half8 __attribute__((ext_vector_type(8)));

__device__ __forceinline__ float lrelu(float x){ return x >= 0.f ? x : 0.01f*x; }

// LDS union across phases (max ~55.8 KB -> 1 block/CU at 250 blocks)
union SharedU {
    struct {                                    // phase 0: nn1 + LSH  (~22.2 KB)
        float bufX[12 * NB];
        float bufA[125 * NB];
        float bufB[125 * NB];
        float sCB[300];
    } p0;
    struct {                                    // phase 1: scatter    (20.1 KB)
        int sBI[NN];
        int s_lt[10];
        int s_eq[10];
    } p1;
    struct {                                    // phase 2: build+conv (~55.8 KB)
        _Float16 M[MROWS * BPAD];
        float s_h[BINSZ * 12];
        int   s_nodes[BINSZ];
        float s_dis[BINSZ];
        float s_w[12 * 32];
        union {
            unsigned s_tv[200 * KNN];           // top-k keys (build)
            struct { float hWd[32 * BPAD]; float gcn[32 * BPAD]; } c;  // conv
        } u;
    } p2;
    struct {                                    // phase 3: nn23       (~28.2 KB)
        float sAG[32 * NB];
        float sGC[32 * NB];
        float bufC[38 * NB];
        float bufA[125 * NB];
        float bufB[125 * NB];
    } p3;
};

// device-scope grid barrier; bar[] zeroed by init_kernel each launch.
__device__ __forceinline__ void gbar(int* bar, int idx) {
    __syncthreads();
    if (threadIdx.x == 0) {
        __threadfence();   // release
        __hip_atomic_fetch_add(bar + idx, 1, __ATOMIC_RELEASE, __HIP_MEMORY_SCOPE_AGENT);
        while (__hip_atomic_load(bar + idx, __ATOMIC_ACQUIRE, __HIP_MEMORY_SCOPE_AGENT) < NBLK)
            __builtin_amdgcn_s_sleep(1);
        __threadfence();   // acquire
    }
    __syncthreads();
}

__global__ void init_kernel(int* bar) {
    if (threadIdx.x < 8) bar[threadIdx.x] = 0;
}

__global__ __launch_bounds__(640, 3) void fused_kernel(
    const float* __restrict__ x,
    const float4* __restrict__ ygen_id4, const float4* __restrict__ ygen4,
    const float* __restrict__ cb,
    const float* __restrict__ W1, const float* __restrict__ b1,
    const float* __restrict__ W2, const float* __restrict__ b2,
    const float* __restrict__ W3, const float* __restrict__ b3,
    const float* __restrict__ gcn_W, const float* __restrict__ gcn_b,
    const float* __restrict__ Wrel, const float* __restrict__ brel,
    const float* __restrict__ Wroot,
    const float* __restrict__ A1, const float* __restrict__ ab1,
    const float* __restrict__ A2, const float* __restrict__ ab2,
    const float* __restrict__ A3, const float* __restrict__ ab3,
    const float* __restrict__ B1, const float* __restrict__ bb1,
    const float* __restrict__ B2, const float* __restrict__ bb2,
    const float* __restrict__ B3, const float* __restrict__ bb3,
    float* __restrict__ h, float* __restrict__ gcn_n, float* __restrict__ agg_n,
    int* __restrict__ bin_idx, int* __restrict__ order, int* __restrict__ bar,
    float* __restrict__ out_ids, float* __restrict__ out_p4,
    float4* __restrict__ out4)
{
    __shared__ SharedU S;
    int tid = threadIdx.x;

    // ================= phase 0: fused MLP1 + LSH bin (all 250 blocks) =============
    {
        int n0 = blockIdx.x * NB;
        int g = tid >> 7, j = tid & 127;
        float acc[4];

        if (tid < 60) {
            float4 v = ((const float4*)(x + n0 * 12))[tid];
            int e = tid * 4;
            S.p0.bufX[(e % 12) * NB + (e / 12)] = v.x;
            S.p0.bufX[((e + 1) % 12) * NB + ((e + 1) / 12)] = v.y;
            S.p0.bufX[((e + 2) % 12) * NB + ((e + 2) / 12)] = v.z;
            S.p0.bufX[((e + 3) % 12) * NB + ((e + 3) / 12)] = v.w;
        }
        if (tid < 300) { int k = tid / 25, c = tid - k * 25; S.p0.sCB[tid] = cb[k * 100 + c]; }
        __syncthreads();

        // L1: 12 -> 125 (weights direct from L2, fully unrolled)
        if (j < 125) {
            float bj = b1[j];
            acc[0] = bj; acc[1] = bj; acc[2] = bj; acc[3] = bj;
            #pragma unroll
            for (int k = 0; k < 12; ++k) {
                float w = W1[k * 125 + j];
                float4 a = *(const float4*)&S.p0.bufX[k * NB + g * 4];
                acc[0] += a.x * w; acc[1] += a.y * w; acc[2] += a.z * w; acc[3] += a.w * w;
            }
            #pragma unroll
            for (int n = 0; n < 4; ++n) S.p0.bufA[j * NB + g * 4 + n] = lrelu(acc[n]);
        }
        __syncthreads();

        // L2: 125 -> 125 (direct weights, unroll 25 for deep load pipelining)
        if (j < 125) {
            float bj = b2[j];
            acc[0] = bj; acc[1] = bj; acc[2] = bj; acc[3] = bj;
            #pragma unroll 25
            for (int k = 0; k < 125; ++k) {
                float w = W2[k * 125 + j];
                float4 a = *(const float4*)&S.p0.bufA[k * NB + g * 4];
                acc[0] += a.x * w; acc[1] += a.y * w; acc[2] += a.z * w; acc[3] += a.w * w;
            }
            #pragma unroll
            for (int n = 0; n < 4; ++n) S.p0.bufB[j * NB + g * 4 + n] = lrelu(acc[n]);
        }
        __syncthreads();

        // L3: 125 -> 12, 4-way k-split, compile-time trip counts
        if (j < 48) {
            int jj = j % 12, s = j / 12;
            float ps[4] = {0.f, 0.f, 0.f, 0.f};
            if (s < 3) {
                int k0 = s * 32;
                #pragma unroll
                for (int k = 0; k < 32; ++k) {
                    float w = W3[(k0 + k) * 12 + jj];
                    float4 a = *(const float4*)&S.p0.bufB[(k0 + k) * NB + g * 4];
                    ps[0] += a.x * w; ps[1] += a.y * w; ps[2] += a.z * w; ps[3] += a.w * w;
                }
            } else {
                #pragma unroll
                for (int k = 0; k < 29; ++k) {
                    float w = W3[(96 + k) * 12 + jj];
                    float4 a = *(const float4*)&S.p0.bufB[(96 + k) * NB + g * 4];
                    ps[0] += a.x * w; ps[1] += a.y * w; ps[2] += a.z * w; ps[3] += a.w * w;
                }
            }
            #pragma unroll
            for (int n = 0; n < 4; ++n) S.p0.bufA[(s * 12 + jj) * NB + g * 4 + n] = ps[n];
        }
        __syncthreads();
        if (tid < 240) {
            int jj = tid / 20, n = tid % 20;
            float v = S.p0.bufA[jj * NB + n] + S.p0.bufA[(12 + jj) * NB + n]
                    + S.p0.bufA[(24 + jj) * NB + n] + S.p0.bufA[(36 + jj) * NB + n] + b3[jj];
            h[(n0 + n) * 12 + jj] = v;
            S.p0.bufB[jj * NB + n] = v;
        }
        __syncthreads();

        // LSH bin (argmax over [mul,-mul], first max wins)
        if (tid < NB) {
            int n = tid;
            float hv[12];
            #pragma unroll
            for (int k = 0; k < 12; ++k) hv[k] = S.p0.bufB[k * NB + n];
            float best = -INFINITY; int bi = 0;
            for (int c = 0; c < 25; ++c) {
                float m = 0.f;
                #pragma unroll
                for (int k = 0; k < 12; ++k) m += hv[k] * S.p0.sCB[k * 25 + c];
                if (m > best) { best = m; bi = c; }
            }
            for (int c = 0; c < 25; ++c) {
                float m = 0.f;
                #pragma unroll
                for (int k = 0; k < 12; ++k) m += hv[k] * S.p0.sCB[k * 25 + c];
                if (-m > best) { best = -m; bi = c + 25; }
            }
            bin_idx[n0 + n] = bi;
        }
    }
    gbar(bar, 0);

    // ======= phase 1: stable argsort-by-bin, 10 waves/bin (blocks 0..49);
    //         ygen passthrough on otherwise-idle blocks 50..249 ====================
    if (blockIdx.x < NBINS) {
        int bb = blockIdx.x;
        for (int t = tid; t < NN / 4; t += 640) ((int4*)S.p1.sBI)[t] = ((const int4*)bin_idx)[t];
        __syncthreads();
        int lane = tid & 63, w = tid >> 6;
        int start = w * 512;
        int end = (start + 512 > NN) ? NN : start + 512;
        int cnt_lt = 0, cnt_eq = 0;
        for (int base = start; base < end; base += 64) {
            int i = base + lane;
            int bi = (i < end) ? S.p1.sBI[i] : 999;
            cnt_lt += __popcll(__ballot(bi < bb));
            cnt_eq += __popcll(__ballot(bi == bb));
        }
        if (lane == 0) { S.p1.s_lt[w] = cnt_lt; S.p1.s_eq[w] = cnt_eq; }
        __syncthreads();
        int offs = 0;
        #pragma unroll
        for (int w2 = 0; w2 < 10; ++w2) {
            offs += S.p1.s_lt[w2];
            if (w2 < w) offs += S.p1.s_eq[w2];
        }
        unsigned long long below = lane ? ((~0ULL) >> (64 - lane)) : 0ULL;
        for (int base = start; base < end; base += 64) {
            int i = base + lane;
            int bi = (i < end) ? S.p1.sBI[i] : 999;
            unsigned long long m = __ballot(bi == bb);
            if (bi == bb) order[offs + __popcll(m & below)] = i;
            offs += __popcll(m);
        }
    } else {
        if (tid < 75) {
            int gI = ((int)blockIdx.x - NBINS) * 75 + tid;   // 200 blocks x 75 = 15000
            out4[15000 + gI] = (gI < 7500) ? ygen_id4[gI] : ygen4[gI - 7500];
        }
    }
    gbar(bar, 1);

    // ======= phase 2: build M (LDS-resident) + conv, one block per bin ===========
    if (blockIdx.x < NBINS) {
        int p = blockIdx.x;
        if (tid < BINSZ) S.p2.s_nodes[tid] = order[p * BINSZ + tid];
        for (int t = tid; t < MROWS * BPAD / 2; t += 640) ((int*)S.p2.M)[t] = 0;
        if (tid < 384) S.p2.s_w[tid] = gcn_W[tid];           // [12][32] row-major
        __syncthreads();
        for (int t = tid; t < BINSZ * 12; t += 640) {
            int i = t / 12, k = t - i * 12;
            S.p2.s_h[t] = h[S.p2.s_nodes[i] * 12 + k];
        }
        __syncthreads();

        // local top-16 over 50 candidates (row = tid>>1, half = tid&1), packed keys
        if (tid < 200) {
            int row = tid >> 1, half = tid & 1;
            const float4* xp = (const float4*)&S.p2.s_h[row * 12];
            float4 x0 = xp[0], x1 = xp[1], x2 = xp[2];
            unsigned tv[KNN];
            #pragma unroll
            for (int k = 0; k < KNN; ++k) tv[k] = 0u;
            int j0 = half * 50;
            for (int jj = 0; jj < 50; ++jj) {
                int jn = j0 + jj;
                const float4* ap = (const float4*)&S.p2.s_h[jn * 12];
                float4 a0 = ap[0], a1 = ap[1], a2 = ap[2];
                float d = x0.x*a0.x + x0.y*a0.y + x0.z*a0.z + x0.w*a0.w
                        + x1.x*a1.x + x1.y*a1.y + x1.z*a1.z + x1.w*a1.w
                        + x2.x*a2.x + x2.y*a2.y + x2.z*a2.z + x2.w*a2.w;
                float v = 1.f / (1.f + expf(-d));
                unsigned key = (__float_as_uint(v) & 0xFFFFFF80u) | (unsigned)(127 - jn);
                if (key > tv[KNN - 1]) {
                    unsigned ins = key;
                    #pragma unroll
                    for (int k = 0; k < KNN; ++k) {
                        bool gt = ins > tv[k];
                        unsigned mx = gt ? ins : tv[k];
                        unsigned mn = gt ? tv[k] : ins;
                        tv[k] = mx; ins = mn;
                    }
                }
            }
            #pragma unroll
            for (int k = 0; k < KNN; ++k) S.p2.u.s_tv[tid * KNN + k] = tv[k];
        }
        __syncthreads();

        // merge two sorted 16-lists into M
        if (tid < BINSZ) {
            int mbase = tid * 32;
            int ia = 0, ib = 0;
            #pragma unroll
            for (int k = 0; k < KNN; ++k) {
                unsigned av = S.p2.u.s_tv[mbase + ia], bv = S.p2.u.s_tv[mbase + 16 + ib];
                bool tA = av > bv;
                unsigned key = tA ? av : bv;
                ia += tA; ib += !tA;
                int ix = 127 - (int)(key & 127u);
                S.p2.M[ix * BPAD + tid] = (_Float16)__uint_as_float(key & 0xFFFFFF80u);
            }
        }
        __syncthreads();
        if (tid < BINSZ) {
            float dsum = 1.0f;
            #pragma unroll 13
            for (int sc = 0; sc < 13; ++sc) {
                half8 m = *(const half8*)&S.p2.M[tid * BPAD + sc * 8];
                dsum += (float)m[0] + (float)m[1] + (float)m[2] + (float)m[3]
                      + (float)m[4] + (float)m[5] + (float)m[6] + (float)m[7];
            }
            S.p2.s_dis[tid] = 1.0f / sqrtf(dsum);
        }
        __syncthreads();     // s_tv dead from here; union region becomes hWd/gcn

        if (tid < 256) {     // zero pad cols 100..103 for all 32 channels
            int c = tid >> 3, r = tid & 7;
            if (r < 4) S.p2.u.c.hWd[c * BPAD + 100 + r] = 0.f;
            else       S.p2.u.c.gcn[c * BPAD + 100 + (r - 4)] = 0.f;
        }
        for (int o = tid; o < BINSZ * 32; o += 640) {
            int s = o >> 5, c = o & 31;
            float a = 0.f;
            #pragma unroll
            for (int k = 0; k < 12; ++k) a += lrelu(S.p2.s_h[s * 12 + k]) * S.p2.s_w[k * 32 + c];
            S.p2.u.c.hWd[c * BPAD + s] = S.p2.s_dis[s] * a;
        }
        __syncthreads();

        // GCN pass: 640 threads = 32 ch x 20 dst-groups, 5 r-slices (exact cover)
        {
            int c = tid / 20, dg = tid % 20;
            float acc5[5];
            #pragma unroll
            for (int r = 0; r < 5; ++r) acc5[r] = 0.f;
            for (int sc = 0; sc < 13; ++sc) {
                float4 hv0 = *(const float4*)&S.p2.u.c.hWd[c * BPAD + sc * 8];
                float4 hv1 = *(const float4*)&S.p2.u.c.hWd[c * BPAD + sc * 8 + 4];
                #pragma unroll
                for (int r = 0; r < 5; ++r) {
                    int d = dg + 20 * r;
                    half8 m = *(const half8*)&S.p2.M[d * BPAD + sc * 8];
                    acc5[r] += (float)m[0]*hv0.x + (float)m[1]*hv0.y + (float)m[2]*hv0.z + (float)m[3]*hv0.w
                             + (float)m[4]*hv1.x + (float)m[5]*hv1.y + (float)m[6]*hv1.z + (float)m[7]*hv1.w;
                }
            }
            float bc = gcn_b[c];
            #pragma unroll
            for (int r = 0; r < 5; ++r) {
                int d = dg + 20 * r;
                float gq = S.p2.s_dis[d] * (acc5[r] + S.p2.u.c.hWd[c * BPAD + d]) + bc;
                S.p2.u.c.gcn[c * BPAD + d] = gq;
                gcn_n[S.p2.s_nodes[d] * 32 + c] = gq;
            }
        }
        __syncthreads();
        // GraphConv aggregate pass
        {
            int c = tid / 20, dg = tid % 20;
            float acc5[5];
            #pragma unroll
            for (int r = 0; r < 5; ++r) acc5[r] = 0.f;
            for (int sc = 0; sc < 13; ++sc) {
                float4 hv0 = *(const float4*)&S.p2.u.c.gcn[c * BPAD + sc * 8];
                float4 hv1 = *(const float4*)&S.p2.u.c.gcn[c * BPAD + sc * 8 + 4];
                #pragma unroll
                for (int r = 0; r < 5; ++r) {
                    int d = dg + 20 * r;
                    half8 m = *(const half8*)&S.p2.M[d * BPAD + sc * 8];
                    acc5[r] += (float)m[0]*hv0.x + (float)m[1]*hv0.y + (float)m[2]*hv0.z + (float)m[3]*hv0.w
                             + (float)m[4]*hv1.x + (float)m[5]*hv1.y + (float)m[6]*hv1.z + (float)m[7]*hv1.w;
                }
            }
            #pragma unroll
            for (int r = 0; r < 5; ++r) {
                int d = dg + 20 * r;
                agg_n[S.p2.s_nodes[d] * 32 + c] = acc5[r];
            }
        }
    }
    gbar(bar, 2);

    // ================= phase 3: combine + nn2 + nn3 (all 250 blocks) =============
    {
        int n0 = blockIdx.x * NB;
        int g = tid >> 7, j = tid & 127;
        float acc[4];

        if (tid < 160) {
            float4 va = ((const float4*)(agg_n + n0 * 32))[tid];
            float4 vg = ((const float4*)(gcn_n + n0 * 32))[tid];
            int e = tid * 4, n = e / 32, k = e % 32;
            S.p3.sAG[k * NB + n] = va.x; S.p3.sAG[(k+1) * NB + n] = va.y;
            S.p3.sAG[(k+2) * NB + n] = va.z; S.p3.sAG[(k+3) * NB + n] = va.w;
            S.p3.sGC[k * NB + n] = vg.x; S.p3.sGC[(k+1) * NB + n] = vg.y;
            S.p3.sGC[(k+2) * NB + n] = vg.z; S.p3.sGC[(k+3) * NB + n] = vg.w;
        }
        __syncthreads();

        // combine: bufC[jc][n] = leaky(agg@Wrel + brel + gcn@Wroot), direct weights
        {
            int jc = tid / 20, n = tid % 20;
            float a = brel[jc];
            #pragma unroll 16
            for (int k = 0; k < 32; ++k)
                a += S.p3.sAG[k * NB + n] * Wrel[k * 32 + jc]
                   + S.p3.sGC[k * NB + n] * Wroot[k * 32 + jc];
            S.p3.bufC[jc * NB + n] = lrelu(a);
        }
        __syncthreads();

        // nn2 L1: 32 -> 125
        if (j < 125) {
            float bj = ab1[j];
            acc[0] = bj; acc[1] = bj; acc[2] = bj; acc[3] = bj;
            #pragma unroll 16
            for (int k = 0; k < 32; ++k) {
                float w = A1[k * 125 + j];
                float4 a = *(const float4*)&S.p3.bufC[k * NB + g * 4];
                acc[0] += a.x * w; acc[1] += a.y * w; acc[2] += a.z * w; acc[3] += a.w * w;
            }
            #pragma unroll
            for (int n = 0; n < 4; ++n) S.p3.bufA[j * NB + g * 4 + n] = lrelu(acc[n]);
        }
        __syncthreads();

        // nn2 L2: 125 -> 125
        if (j < 125) {
            float bj = ab2[j];
            acc[0] = bj; acc[1] = bj; acc[2] = bj; acc[3] = bj;
            #pragma unroll 25
            for (int k = 0; k < 125; ++k) {
                float w = A2[k * 125 + j];
                float4 a = *(const float4*)&S.p3.bufA[k * NB + g * 4];
                acc[0] += a.x * w; acc[1] += a.y * w; acc[2] += a.z * w; acc[3] += a.w * w;
            }
            #pragma unroll
            for (int n = 0; n < 4; ++n) S.p3.bufB[j * NB + g * 4 + n] = lrelu(acc[n]);
        }
        __syncthreads();

        // nn2 L3: 125 -> 6, 4-way k-split
        if (j < 24) {
            int jj = j % 6, s = j / 6;
            float ps[4] = {0.f, 0.f, 0.f, 0.f};
            if (s < 3) {
                int k0 = s * 32;
                #pragma unroll
                for (int k = 0; k < 32; ++k) {
                    float w = A3[(k0 + k) * 6 + jj];
                    float4 a = *(const float4*)&S.p3.bufB[(k0 + k) * NB + g * 4];
                    ps[0] += a.x * w; ps[1] += a.y * w; ps[2] += a.z * w; ps[3] += a.w * w;
                }
            } else {
                #pragma unroll
                for (int k = 0; k < 29; ++k) {
                    float w = A3[(96 + k) * 6 + jj];
                    float4 a = *(const float4*)&S.p3.bufB[(96 + k) * NB + g * 4];
                    ps[0] += a.x * w; ps[1] += a.y * w; ps[2] += a.z * w; ps[3] += a.w * w;
                }
            }
            #pragma unroll
            for (int n = 0; n < 4; ++n) S.p3.bufA[(s * 6 + jj) * NB + g * 4 + n] = ps[n];
        }
        __syncthreads();
        if (tid < 120) {
            int jj = tid / 20, n = tid % 20;
            float v = S.p3.bufA[jj * NB + n] + S.p3.bufA[(6 + jj) * NB + n]
                    + S.p3.bufA[(12 + jj) * NB + n] + S.p3.bufA[(18 + jj) * NB + n] + ab3[jj];
            out_ids[(n0 + n) * 6 + jj] = v;
            S.p3.bufC[(32 + jj) * NB + n] = v;
        }
        __syncthreads();

        // nn3 L1: 38 -> 125
        if (j < 125) {
            float bj = bb1[j];
            acc[0] = bj; acc[1] = bj; acc[2] = bj; acc[3] = bj;
            #pragma unroll 19
            for (int k = 0; k < 38; ++k) {
                float w = B1[k * 125 + j];
                float4 a = *(const float4*)&S.p3.bufC[k * NB + g * 4];
                acc[0] += a.x * w; acc[1] += a.y * w; acc[2] += a.z * w; acc[3] += a.w * w;
            }
            #pragma unroll
            for (int n = 0; n < 4; ++n) S.p3.bufA[j * NB + g * 4 + n] = lrelu(acc[n]);
        }
        __syncthreads();

        // nn3 L2: 125 -> 125
        if (j < 125) {
            float bj = bb2[j];
            acc[0] = bj; acc[1] = bj; acc[2] = bj; acc[3] = bj;
            #pragma unroll 25
            for (int k = 0; k < 125; ++k) {
                float w = B2[k * 125 + j];
                float4 a = *(const float4*)&S.p3.bufA[k * NB + g * 4];
                acc[0] += a.x * w; acc[1] += a.y * w; acc[2] += a.z * w; acc[3] += a.w * w;
            }
            #pragma unroll
            for (int n = 0; n < 4; ++n) S.p3.bufB[j * NB + g * 4 + n] = lrelu(acc[n]);
        }
        __syncthreads();

        // nn3 L3: 125 -> 6, 4-way k-split
        if (j < 24) {
            int jj = j % 6, s = j / 6;
            float ps[4] = {0.f, 0.f, 0.f, 0.f};
            if (s < 3) {
                int k0 = s * 32;
                #pragma unroll
                for (int k = 0; k < 32; ++k) {
                    float w = B3[(k0 + k) * 6 + jj];
                    float4 a = *(const float4*)&S.p3.bufB[(k0 + k) * NB + g * 4];
                    ps[0] += a.x * w; ps[1] += a.y * w; ps[2] += a.z * w; ps[3] += a.w * w;
                }
            } else {
                #pragma unroll
                for (int k = 0; k < 29; ++k) {
                    float w = B3[(96 + k) * 6 + jj];
                    float4 a = *(const float4*)&S.p3.bufB[(96 + k) * NB + g * 4];
                    ps[0] += a.x * w; ps[1] += a.y * w; ps[2] += a.z * w; ps[3] += a.w * w;
                }
            }
            #pragma unroll
            for (int n = 0; n < 4; ++n) S.p3.bufA[(s * 6 + jj) * NB + g * 4 + n] = ps[n];
        }
        __syncthreads();
        if (tid < 120) {
            int jj = tid / 20, n = tid % 20;
            float v = S.p3.bufA[jj * NB + n] + S.p3.bufA[(6 + jj) * NB + n]
                    + S.p3.bufA[(12 + jj) * NB + n] + S.p3.bufA[(18 + jj) * NB + n] + bb3[jj];
            out_p4[(n0 + n) * 6 + jj] = v;
        }
    }
}

extern "C" void kernel_launch(void* const* d_in, const int* in_sizes, int n_in,
                              void* d_out, int out_size, void* d_ws, size_t ws_size,
                              hipStream_t stream) {
    const float* x        = (const float*)d_in[0];
    const float* ygen_id  = (const float*)d_in[1];
    const float* ygen     = (const float*)d_in[2];
    const float* codebook = (const float*)d_in[3];
    const float* nn1_W1 = (const float*)d_in[4];  const float* nn1_b1 = (const float*)d_in[5];
    const float* nn1_W2 = (const float*)d_in[6];  const float* nn1_b2 = (const float*)d_in[7];
    const float* nn1_W3 = (const float*)d_in[8];  const float* nn1_b3 = (const float*)d_in[9];
    const float* gcn_W  = (const float*)d_in[10]; const float* gcn_b  = (const float*)d_in[11];
    const float* gc_Wrel = (const float*)d_in[12]; const float* gc_brel = (const float*)d_in[13];
    const float* gc_Wroot = (const float*)d_in[14];
    const float* nn2_W1 = (const float*)d_in[15]; const float* nn2_b1 = (const float*)d_in[16];
    const float* nn2_W2 = (const float*)d_in[17]; const float* nn2_b2 = (const float*)d_in[18];
    const float* nn2_W3 = (const float*)d_in[19]; const float* nn2_b3 = (const float*)d_in[20];
    const float* nn3_W1 = (const float*)d_in[21]; const float* nn3_b1 = (const float*)d_in[22];
    const float* nn3_W2 = (const float*)d_in[23]; const float* nn3_b2 = (const float*)d_in[24];
    const float* nn3_W3 = (const float*)d_in[25]; const float* nn3_b3 = (const float*)d_in[26];

    float* out = (float*)d_out;
    float* ws  = (float*)d_ws;

    float* h      = ws + 0;         // 60000
    float* gcn_n  = ws + 60000;     // 160000
    float* agg_n  = ws + 220000;    // 160000
    int* bin_idx  = (int*)(ws + 380000);  // 5000
    int* order    = (int*)(ws + 385000);  // 5000
    int* bar      = (int*)(ws + 390000);  // 8

    init_kernel<<<1, 64, 0, stream>>>(bar);

    fused_kernel<<<NBLK, 640, 0, stream>>>(
        x, (const float4*)ygen_id, (const float4*)ygen, codebook,
        nn1_W1, nn1_b1, nn1_W2, nn1_b2, nn1_W3, nn1_b3,
        gcn_W, gcn_b, gc_Wrel, gc_brel, gc_Wroot,
        nn2_W1, nn2_b1, nn2_W2, nn2_b2, nn2_W3, nn2_b3,
        nn3_W1, nn3_b1, nn3_W2, nn3_b2, nn3_W3, nn3_b3,
        h, gcn_n, agg_n, bin_idx, order, bar,
        out, out + 30000, (float4*)out);
}

// Round 3
// 177.605 us; speedup vs baseline: 1.4830x; 1.4830x over previous
//
#include <hip/hip_runtime.h>
#include <math.h>

#define NN 5000
#define NBINS 50
#define BINSZ 100
#define KNN 16
#define BPAD 104          // padded M row length (halves); 208 B stride, 16B aligned
#define MROWS 112         // padded row count in conv phase
#define NB 20             // nodes per block in MLP kernels (5 groups x 4)

typedef _Float16 half8 __attribute__((ext_vector_type(8)));

__device__ __forceinline__ float lrelu(float x){ return x >= 0.f ? x : 0.01f*x; }

// ============ kernel 1: nn1 + LSH bin + ygen passthrough (250 x 640) ============
// LDS 94.4 KB: whole W1|W2|W3 staged once; all inner loops compile-time trip.
__global__ __launch_bounds__(640) void nn1_kernel(
    const float* __restrict__ x,
    const float* __restrict__ W1, const float* __restrict__ b1,
    const float* __restrict__ W2, const float* __restrict__ b2,
    const float* __restrict__ W3, const float* __restrict__ b3,
    const float* __restrict__ cb,
    const float4* __restrict__ ygen_id4, const float4* __restrict__ ygen4,
    float4* __restrict__ out4,
    float* __restrict__ h_out, int* __restrict__ bin_idx)
{
    __shared__ __align__(16) float sW[18628];   // W1 [0,1500) W2 [1500,17125) W3 [17128,18628)
    __shared__ __align__(16) float bufX[240];   // x transposed [k][n]
    __shared__ __align__(16) float bufA[2500];
    __shared__ __align__(16) float bufB[2500];
    __shared__ __align__(16) float sCB[300];
    int tid = threadIdx.x;
    int n0 = blockIdx.x * NB;
    int g = tid >> 7, j = tid & 127;
    float acc[4];

    // ygen passthrough on otherwise-idle lanes: 250 blocks x 60 float4 = 15000
    if (tid >= 576 && tid < 636) {
        int gI = blockIdx.x * 60 + (tid - 576);
        out4[15000 + gI] = (gI < 7500) ? ygen_id4[gI] : ygen4[gI - 7500];
    }
    // stage x (transposed), codebook, and ALL weights (one sync)
    if (tid < 60) {
        float4 v = ((const float4*)(x + n0 * 12))[tid];
        int e = tid * 4;
        bufX[(e % 12) * NB + (e / 12)] = v.x;
        bufX[((e + 1) % 12) * NB + ((e + 1) / 12)] = v.y;
        bufX[((e + 2) % 12) * NB + ((e + 2) / 12)] = v.z;
        bufX[((e + 3) % 12) * NB + ((e + 3) / 12)] = v.w;
    }
    if (tid >= 60 && tid < 360) {
        int t = tid - 60; int k = t / 25, c = t - k * 25;
        sCB[t] = cb[k * 100 + c];
    }
    for (int t = tid; t < 375; t += 640) ((float4*)sW)[t] = ((const float4*)W1)[t];
    for (int t = tid; t < 3906; t += 640) ((float4*)(sW + 1500))[t] = ((const float4*)W2)[t];
    if (tid == 636) sW[1500 + 15624] = W2[15624];
    for (int t = tid; t < 375; t += 640) ((float4*)(sW + 17128))[t] = ((const float4*)W3)[t];
    __syncthreads();

    // L1: 12 -> 125
    if (j < 125) {
        float bj = b1[j];
        acc[0] = bj; acc[1] = bj; acc[2] = bj; acc[3] = bj;
        #pragma unroll
        for (int k = 0; k < 12; ++k) {
            float w = sW[k * 125 + j];
            float4 a = *(const float4*)&bufX[k * NB + g * 4];
            acc[0] += a.x * w; acc[1] += a.y * w; acc[2] += a.z * w; acc[3] += a.w * w;
        }
        #pragma unroll
        for (int n = 0; n < 4; ++n) bufA[j * NB + g * 4 + n] = lrelu(acc[n]);
    }
    __syncthreads();

    // L2: 125 -> 125, single unrolled loop over staged W2
    if (j < 125) {
        float bj = b2[j];
        acc[0] = bj; acc[1] = bj; acc[2] = bj; acc[3] = bj;
        #pragma unroll 25
        for (int k = 0; k < 125; ++k) {
            float w = sW[1500 + k * 125 + j];
            float4 a = *(const float4*)&bufA[k * NB + g * 4];
            acc[0] += a.x * w; acc[1] += a.y * w; acc[2] += a.z * w; acc[3] += a.w * w;
        }
        #pragma unroll
        for (int n = 0; n < 4; ++n) bufB[j * NB + g * 4 + n] = lrelu(acc[n]);
    }
    __syncthreads();

    // L3: 125 -> 12, 4-way k-split, compile-time trips
    if (j < 48) {
        int jj = j % 12, s = j / 12;
        float ps[4] = {0.f, 0.f, 0.f, 0.f};
        if (s < 3) {
            int k0 = s * 32;
            #pragma unroll
            for (int k = 0; k < 32; ++k) {
                float w = sW[17128 + (k0 + k) * 12 + jj];
                float4 a = *(const float4*)&bufB[(k0 + k) * NB + g * 4];
                ps[0] += a.x * w; ps[1] += a.y * w; ps[2] += a.z * w; ps[3] += a.w * w;
            }
        } else {
            #pragma unroll
            for (int k = 0; k < 29; ++k) {
                float w = sW[17128 + (96 + k) * 12 + jj];
                float4 a = *(const float4*)&bufB[(96 + k) * NB + g * 4];
                ps[0] += a.x * w; ps[1] += a.y * w; ps[2] += a.z * w; ps[3] += a.w * w;
            }
        }
        #pragma unroll
        for (int n = 0; n < 4; ++n) bufA[(s * 12 + jj) * NB + g * 4 + n] = ps[n];
    }
    __syncthreads();
    if (tid < 240) {
        int jj = tid / 20, n = tid % 20;
        float v = bufA[jj * NB + n] + bufA[(12 + jj) * NB + n]
                + bufA[(24 + jj) * NB + n] + bufA[(36 + jj) * NB + n] + b3[jj];
        h_out[(n0 + n) * 12 + jj] = v;
        bufB[jj * NB + n] = v;
    }
    __syncthreads();

    // LSH bin: mvals in parallel (500 thr), then first-max-wins scan (20 thr)
    if (tid < 500) {
        int n = tid / 25, c = tid % 25;
        float m = 0.f;
        #pragma unroll
        for (int k = 0; k < 12; ++k) m += bufB[k * NB + n] * sCB[k * 25 + c];
        bufA[c * NB + n] = m;
    }
    __syncthreads();
    if (tid < NB) {
        int n = tid;
        float best = -INFINITY; int bi = 0;
        #pragma unroll
        for (int c = 0; c < 25; ++c) {
            float m = bufA[c * NB + n];
            if (m > best) { best = m; bi = c; }
        }
        #pragma unroll
        for (int c = 0; c < 25; ++c) {
            float m = -bufA[c * NB + n];
            if (m > best) { best = m; bi = c + 25; }
        }
        bin_idx[n0 + n] = bi;
    }
}

// ============ kernel 2: stable argsort-by-bin, 10 waves/bin (50 x 640) ==========
__global__ __launch_bounds__(640) void scatter_kernel(
    const int* __restrict__ bin_idx, int* __restrict__ order)
{
    __shared__ int sBI[NN];
    __shared__ int s_lt[10], s_eq[10];
    int tid = threadIdx.x, bb = blockIdx.x;
    for (int t = tid; t < NN / 4; t += 640) ((int4*)sBI)[t] = ((const int4*)bin_idx)[t];
    __syncthreads();
    int lane = tid & 63, w = tid >> 6;
    int start = w * 512;
    int end = (start + 512 > NN) ? NN : start + 512;
    int cnt_lt = 0, cnt_eq = 0;
    for (int base = start; base < end; base += 64) {
        int i = base + lane;
        int bi = (i < end) ? sBI[i] : 999;
        cnt_lt += __popcll(__ballot(bi < bb));
        cnt_eq += __popcll(__ballot(bi == bb));
    }
    if (lane == 0) { s_lt[w] = cnt_lt; s_eq[w] = cnt_eq; }
    __syncthreads();
    int offs = 0;
    #pragma unroll
    for (int w2 = 0; w2 < 10; ++w2) {
        offs += s_lt[w2];
        if (w2 < w) offs += s_eq[w2];
    }
    unsigned long long below = lane ? ((~0ULL) >> (64 - lane)) : 0ULL;
    for (int base = start; base < end; base += 64) {
        int i = base + lane;
        int bi = (i < end) ? sBI[i] : 999;
        unsigned long long m = __ballot(bi == bb);
        if (bi == bb) order[offs + __popcll(m & below)] = i;
        offs += __popcll(m);
    }
}

// ============ kernel 3: build M (LDS-resident) + both convs (50 x 640) ==========
__global__ __launch_bounds__(640) void graph_kernel(
    const float* __restrict__ h, const int* __restrict__ order,
    const float* __restrict__ gcn_W, const float* __restrict__ gcn_b,
    float* __restrict__ gcn_n, float* __restrict__ agg_n)
{
    __shared__ _Float16 M[MROWS * BPAD];
    __shared__ float s_h[BINSZ * 12];
    __shared__ int   s_nodes[BINSZ];
    __shared__ float s_dis[BINSZ];
    __shared__ float s_w[12 * 32];
    __shared__ union {
        unsigned s_tv[200 * KNN];
        struct { float hWd[32 * BPAD]; float gcn[32 * BPAD]; } c;
    } U;
    int p = blockIdx.x, tid = threadIdx.x;

    if (tid < BINSZ) s_nodes[tid] = order[p * BINSZ + tid];
    for (int t = tid; t < MROWS * BPAD / 2; t += 640) ((int*)M)[t] = 0;
    if (tid < 384) s_w[tid] = gcn_W[tid];       // [12][32] row-major
    __syncthreads();
    for (int t = tid; t < BINSZ * 12; t += 640) {
        int i = t / 12, k = t - i * 12;
        s_h[t] = h[s_nodes[i] * 12 + k];
    }
    __syncthreads();

    // local top-16 over 50 candidates (row = tid>>1, half = tid&1), packed keys
    if (tid < 200) {
        int row = tid >> 1, half = tid & 1;
        const float4* xp = (const float4*)&s_h[row * 12];
        float4 x0 = xp[0], x1 = xp[1], x2 = xp[2];
        unsigned tv[KNN];
        #pragma unroll
        for (int k = 0; k < KNN; ++k) tv[k] = 0u;
        int j0 = half * 50;
        for (int jj = 0; jj < 50; ++jj) {
            int jn = j0 + jj;
            const float4* ap = (const float4*)&s_h[jn * 12];
            float4 a0 = ap[0], a1 = ap[1], a2 = ap[2];
            float d = x0.x*a0.x + x0.y*a0.y + x0.z*a0.z + x0.w*a0.w
                    + x1.x*a1.x + x1.y*a1.y + x1.z*a1.z + x1.w*a1.w
                    + x2.x*a2.x + x2.y*a2.y + x2.z*a2.z + x2.w*a2.w;
            float v = 1.f / (1.f + expf(-d));
            unsigned key = (__float_as_uint(v) & 0xFFFFFF80u) | (unsigned)(127 - jn);
            if (key > tv[KNN - 1]) {
                unsigned ins = key;
                #pragma unroll
                for (int k = 0; k < KNN; ++k) {
                    bool gt = ins > tv[k];
                    unsigned mx = gt ? ins : tv[k];
                    unsigned mn = gt ? tv[k] : ins;
                    tv[k] = mx; ins = mn;
                }
            }
        }
        #pragma unroll
        for (int k = 0; k < KNN; ++k) U.s_tv[tid * KNN + k] = tv[k];
    }
    __syncthreads();

    // merge two sorted 16-lists into M (keys embed tie-break)
    if (tid < BINSZ) {
        int mbase = tid * 32;
        int ia = 0, ib = 0;
        #pragma unroll
        for (int k = 0; k < KNN; ++k) {
            unsigned av = U.s_tv[mbase + ia], bv = U.s_tv[mbase + 16 + ib];
            bool tA = av > bv;
            unsigned key = tA ? av : bv;
            ia += tA; ib += !tA;
            int ix = 127 - (int)(key & 127u);
            M[ix * BPAD + tid] = (_Float16)__uint_as_float(key & 0xFFFFFF80u);
        }
    }
    __syncthreads();
    if (tid < BINSZ) {
        float dsum = 1.0f;
        #pragma unroll 13
        for (int sc = 0; sc < 13; ++sc) {
            half8 m = *(const half8*)&M[tid * BPAD + sc * 8];
            dsum += (float)m[0] + (float)m[1] + (float)m[2] + (float)m[3]
                  + (float)m[4] + (float)m[5] + (float)m[6] + (float)m[7];
        }
        s_dis[tid] = 1.0f / sqrtf(dsum);
    }
    __syncthreads();    // s_tv dead from here; union region becomes hWd/gcn

    if (tid < 256) {    // zero pad cols 100..103 for all 32 channels
        int c = tid >> 3, r = tid & 7;
        if (r < 4) U.c.hWd[c * BPAD + 100 + r] = 0.f;
        else       U.c.gcn[c * BPAD + 100 + (r - 4)] = 0.f;
    }
    for (int o = tid; o < BINSZ * 32; o += 640) {
        int s = o >> 5, c = o & 31;
        float a = 0.f;
        #pragma unroll
        for (int k = 0; k < 12; ++k) a += lrelu(s_h[s * 12 + k]) * s_w[k * 32 + c];
        U.c.hWd[c * BPAD + s] = s_dis[s] * a;
    }
    __syncthreads();

    // GCN pass: 640 threads = 32 ch x 20 dst-groups, 5 r-slices (exact cover)
    {
        int c = tid / 20, dg = tid % 20;
        float acc5[5];
        #pragma unroll
        for (int r = 0; r < 5; ++r) acc5[r] = 0.f;
        for (int sc = 0; sc < 13; ++sc) {
            float4 hv0 = *(const float4*)&U.c.hWd[c * BPAD + sc * 8];
            float4 hv1 = *(const float4*)&U.c.hWd[c * BPAD + sc * 8 + 4];
            #pragma unroll
            for (int r = 0; r < 5; ++r) {
                int d = dg + 20 * r;
                half8 m = *(const half8*)&M[d * BPAD + sc * 8];
                acc5[r] += (float)m[0]*hv0.x + (float)m[1]*hv0.y + (float)m[2]*hv0.z + (float)m[3]*hv0.w
                         + (float)m[4]*hv1.x + (float)m[5]*hv1.y + (float)m[6]*hv1.z + (float)m[7]*hv1.w;
            }
        }
        float bc = gcn_b[c];
        #pragma unroll
        for (int r = 0; r < 5; ++r) {
            int d = dg + 20 * r;
            float gq = s_dis[d] * (acc5[r] + U.c.hWd[c * BPAD + d]) + bc;
            U.c.gcn[c * BPAD + d] = gq;
            gcn_n[s_nodes[d] * 32 + c] = gq;
        }
    }
    __syncthreads();
    // GraphConv aggregate pass
    {
        int c = tid / 20, dg = tid % 20;
        float acc5[5];
        #pragma unroll
        for (int r = 0; r < 5; ++r) acc5[r] = 0.f;
        for (int sc = 0; sc < 13; ++sc) {
            float4 hv0 = *(const float4*)&U.c.gcn[c * BPAD + sc * 8];
            float4 hv1 = *(const float4*)&U.c.gcn[c * BPAD + sc * 8 + 4];
            #pragma unroll
            for (int r = 0; r < 5; ++r) {
                int d = dg + 20 * r;
                half8 m = *(const half8*)&M[d * BPAD + sc * 8];
                acc5[r] += (float)m[0]*hv0.x + (float)m[1]*hv0.y + (float)m[2]*hv0.z + (float)m[3]*hv0.w
                         + (float)m[4]*hv1.x + (float)m[5]*hv1.y + (float)m[6]*hv1.z + (float)m[7]*hv1.w;
            }
        }
        #pragma unroll
        for (int r = 0; r < 5; ++r) {
            int d = dg + 20 * r;
            agg_n[s_nodes[d] * 32 + c] = acc5[r];
        }
    }
}

// ============ kernel 4: combine + nn2 + nn3 (250 x 640), LDS 115 KB =============
__global__ __launch_bounds__(640) void nn23_kernel(
    const float* __restrict__ gcn_n, const float* __restrict__ agg_n,
    const float* __restrict__ Wrel, const float* __restrict__ brel,
    const float* __restrict__ Wroot,
    const float* __restrict__ A1, const float* __restrict__ ab1,
    const float* __restrict__ A2, const float* __restrict__ ab2,
    const float* __restrict__ A3, const float* __restrict__ ab3,
    const float* __restrict__ B1, const float* __restrict__ bb1,
    const float* __restrict__ B2, const float* __restrict__ bb2,
    const float* __restrict__ B3, const float* __restrict__ bb3,
    float* __restrict__ out_ids, float* __restrict__ out_p4)
{
    // A-phase layout: Wrel[0,1024) Wroot[1024,2048) A1[2048,6048) A2[6048,21673) A3[21676,22426)
    // B-phase layout: B1[0,4750) B2[4752,20377) B3[20380,21130)
    __shared__ __align__(16) float sW[22428];
    __shared__ __align__(16) float sAG[640];
    __shared__ __align__(16) float sGC[640];
    __shared__ __align__(16) float bufC[760];
    __shared__ __align__(16) float bufA[2500];
    __shared__ __align__(16) float bufB[2500];
    int tid = threadIdx.x;
    int n0 = blockIdx.x * NB;
    int g = tid >> 7, j = tid & 127;
    float acc[4];

    // stage activations (transposed) + all A-phase weights; one sync
    if (tid < 160) {
        float4 va = ((const float4*)(agg_n + n0 * 32))[tid];
        float4 vg = ((const float4*)(gcn_n + n0 * 32))[tid];
        int e = tid * 4, n = e / 32, k = e % 32;
        sAG[k * NB + n] = va.x; sAG[(k+1) * NB + n] = va.y;
        sAG[(k+2) * NB + n] = va.z; sAG[(k+3) * NB + n] = va.w;
        sGC[k * NB + n] = vg.x; sGC[(k+1) * NB + n] = vg.y;
        sGC[(k+2) * NB + n] = vg.z; sGC[(k+3) * NB + n] = vg.w;
    }
    if (tid >= 160 && tid < 416) ((float4*)sW)[tid - 160] = ((const float4*)Wrel)[tid - 160];
    if (tid >= 416 && tid < 636) ((float4*)(sW + 1024))[tid - 416] = ((const float4*)Wroot)[tid - 416];
    if (tid < 36) ((float4*)(sW + 1024))[220 + tid] = ((const float4*)Wroot)[220 + tid];
    for (int t = tid; t < 1000; t += 640) ((float4*)(sW + 2048))[t] = ((const float4*)A1)[t];
    for (int t = tid; t < 3906; t += 640) ((float4*)(sW + 6048))[t] = ((const float4*)A2)[t];
    if (tid == 637) sW[6048 + 15624] = A2[15624];
    if (tid >= 416 && tid < 603) ((float4*)(sW + 21676))[tid - 416] = ((const float4*)A3)[tid - 416];
    if (tid == 638) { sW[21676 + 748] = A3[748]; sW[21676 + 749] = A3[749]; }
    __syncthreads();

    // combine: bufC[jc][n] = leaky(agg@Wrel + brel + gcn@Wroot)
    {
        int jc = tid / 20, n = tid % 20;
        float a = brel[jc];
        #pragma unroll
        for (int k = 0; k < 32; ++k)
            a += sAG[k * NB + n] * sW[k * 32 + jc] + sGC[k * NB + n] * sW[1024 + k * 32 + jc];
        bufC[jc * NB + n] = lrelu(a);
    }
    __syncthreads();

    // nn2 L1: 32 -> 125
    if (j < 125) {
        float bj = ab1[j];
        acc[0] = bj; acc[1] = bj; acc[2] = bj; acc[3] = bj;
        #pragma unroll
        for (int k = 0; k < 32; ++k) {
            float w = sW[2048 + k * 125 + j];
            float4 a = *(const float4*)&bufC[k * NB + g * 4];
            acc[0] += a.x * w; acc[1] += a.y * w; acc[2] += a.z * w; acc[3] += a.w * w;
        }
        #pragma unroll
        for (int n = 0; n < 4; ++n) bufA[j * NB + g * 4 + n] = lrelu(acc[n]);
    }
    __syncthreads();

    // nn2 L2: 125 -> 125
    if (j < 125) {
        float bj = ab2[j];
        acc[0] = bj; acc[1] = bj; acc[2] = bj; acc[3] = bj;
        #pragma unroll 25
        for (int k = 0; k < 125; ++k) {
            float w = sW[6048 + k * 125 + j];
            float4 a = *(const float4*)&bufA[k * NB + g * 4];
            acc[0] += a.x * w; acc[1] += a.y * w; acc[2] += a.z * w; acc[3] += a.w * w;
        }
        #pragma unroll
        for (int n = 0; n < 4; ++n) bufB[j * NB + g * 4 + n] = lrelu(acc[n]);
    }
    __syncthreads();

    // nn2 L3: 125 -> 6, 4-way k-split
    if (j < 24) {
        int jj = j % 6, s = j / 6;
        float ps[4] = {0.f, 0.f, 0.f, 0.f};
        if (s < 3) {
            int k0 = s * 32;
            #pragma unroll
            for (int k = 0; k < 32; ++k) {
                float w = sW[21676 + (k0 + k) * 6 + jj];
                float4 a = *(const float4*)&bufB[(k0 + k) * NB + g * 4];
                ps[0] += a.x * w; ps[1] += a.y * w; ps[2] += a.z * w; ps[3] += a.w * w;
            }
        } else {
            #pragma unroll
            for (int k = 0; k < 29; ++k) {
                float w = sW[21676 + (96 + k) * 6 + jj];
                float4 a = *(const float4*)&bufB[(96 + k) * NB + g * 4];
                ps[0] += a.x * w; ps[1] += a.y * w; ps[2] += a.z * w; ps[3] += a.w * w;
            }
        }
        #pragma unroll
        for (int n = 0; n < 4; ++n) bufA[(s * 6 + jj) * NB + g * 4 + n] = ps[n];
    }
    __syncthreads();
    // reduce nn2 output; concurrently stage B-phase weights (A-region dead)
    if (tid < 120) {
        int jj = tid / 20, n = tid % 20;
        float v = bufA[jj * NB + n] + bufA[(6 + jj) * NB + n]
                + bufA[(12 + jj) * NB + n] + bufA[(18 + jj) * NB + n] + ab3[jj];
        out_ids[(n0 + n) * 6 + jj] = v;
        bufC[(32 + jj) * NB + n] = v;
    }
    for (int t = tid; t < 1187; t += 640) ((float4*)sW)[t] = ((const float4*)B1)[t];
    if (tid == 600) { sW[4748] = B1[4748]; sW[4749] = B1[4749]; }
    for (int t = tid; t < 3906; t += 640) ((float4*)(sW + 4752))[t] = ((const float4*)B2)[t];
    if (tid == 601) sW[4752 + 15624] = B2[15624];
    if (tid >= 256 && tid < 443) ((float4*)(sW + 20380))[tid - 256] = ((const float4*)B3)[tid - 256];
    if (tid == 602) { sW[20380 + 748] = B3[748]; sW[20380 + 749] = B3[749]; }
    __syncthreads();

    // nn3 L1: 38 -> 125
    if (j < 125) {
        float bj = bb1[j];
        acc[0] = bj; acc[1] = bj; acc[2] = bj; acc[3] = bj;
        #pragma unroll 19
        for (int k = 0; k < 38; ++k) {
            float w = sW[k * 125 + j];
            float4 a = *(const float4*)&bufC[k * NB + g * 4];
            acc[0] += a.x * w; acc[1] += a.y * w; acc[2] += a.z * w; acc[3] += a.w * w;
        }
        #pragma unroll
        for (int n = 0; n < 4; ++n) bufA[j * NB + g * 4 + n] = lrelu(acc[n]);
    }
    __syncthreads();

    // nn3 L2: 125 -> 125
    if (j < 125) {
        float bj = bb2[j];
        acc[0] = bj; acc[1] = bj; acc[2] = bj; acc[3] = bj;
        #pragma unroll 25
        for (int k = 0; k < 125; ++k) {
            float w = sW[4752 + k * 125 + j];
            float4 a = *(const float4*)&bufA[k * NB + g * 4];
            acc[0] += a.x * w; acc[1] += a.y * w; acc[2] += a.z * w; acc[3] += a.w * w;
        }
        #pragma unroll
        for (int n = 0; n < 4; ++n) bufB[j * NB + g * 4 + n] = lrelu(acc[n]);
    }
    __syncthreads();

    // nn3 L3: 125 -> 6, 4-way k-split
    if (j < 24) {
        int jj = j % 6, s = j / 6;
        float ps[4] = {0.f, 0.f, 0.f, 0.f};
        if (s < 3) {
            int k0 = s * 32;
            #pragma unroll
            for (int k = 0; k < 32; ++k) {
                float w = sW[20380 + (k0 + k) * 6 + jj];
                float4 a = *(const float4*)&bufB[(k0 + k) * NB + g * 4];
                ps[0] += a.x * w; ps[1] += a.y * w; ps[2] += a.z * w; ps[3] += a.w * w;
            }
        } else {
            #pragma unroll
            for (int k = 0; k < 29; ++k) {
                float w = sW[20380 + (96 + k) * 6 + jj];
                float4 a = *(const float4*)&bufB[(96 + k) * NB + g * 4];
                ps[0] += a.x * w; ps[1] += a.y * w; ps[2] += a.z * w; ps[3] += a.w * w;
            }
        }
        #pragma unroll
        for (int n = 0; n < 4; ++n) bufA[(s * 6 + jj) * NB + g * 4 + n] = ps[n];
    }
    __syncthreads();
    if (tid < 120) {
        int jj = tid / 20, n = tid % 20;
        float v = bufA[jj * NB + n] + bufA[(6 + jj) * NB + n]
                + bufA[(12 + jj) * NB + n] + bufA[(18 + jj) * NB + n] + bb3[jj];
        out_p4[(n0 + n) * 6 + jj] = v;
    }
}

extern "C" void kernel_launch(void* const* d_in, const int* in_sizes, int n_in,
                              void* d_out, int out_size, void* d_ws, size_t ws_size,
                              hipStream_t stream) {
    const float* x        = (const float*)d_in[0];
    const float* ygen_id  = (const float*)d_in[1];
    const float* ygen     = (const float*)d_in[2];
    const float* codebook = (const float*)d_in[3];
    const float* nn1_W1 = (const float*)d_in[4];  const float* nn1_b1 = (const float*)d_in[5];
    const float* nn1_W2 = (const float*)d_in[6];  const float* nn1_b2 = (const float*)d_in[7];
    const float* nn1_W3 = (const float*)d_in[8];  const float* nn1_b3 = (const float*)d_in[9];
    const float* gcn_W  = (const float*)d_in[10]; const float* gcn_b  = (const float*)d_in[11];
    const float* gc_Wrel = (const float*)d_in[12]; const float* gc_brel = (const float*)d_in[13];
    const float* gc_Wroot = (const float*)d_in[14];
    const float* nn2_W1 = (const float*)d_in[15]; const float* nn2_b1 = (const float*)d_in[16];
    const float* nn2_W2 = (const float*)d_in[17]; const float* nn2_b2 = (const float*)d_in[18];
    const float* nn2_W3 = (const float*)d_in[19]; const float* nn2_b3 = (const float*)d_in[20];
    const float* nn3_W1 = (const float*)d_in[21]; const float* nn3_b1 = (const float*)d_in[22];
    const float* nn3_W2 = (const float*)d_in[23]; const float* nn3_b2 = (const float*)d_in[24];
    const float* nn3_W3 = (const float*)d_in[25]; const float* nn3_b3 = (const float*)d_in[26];

    float* out = (float*)d_out;
    float* ws  = (float*)d_ws;

    float* h      = ws + 0;               // 60000
    float* gcn_n  = ws + 60000;           // 160000
    float* agg_n  = ws + 220000;          // 160000
    int* bin_idx  = (int*)(ws + 380000);  // 5000
    int* order    = (int*)(ws + 385000);  // 5000

    nn1_kernel<<<NN / NB, 640, 0, stream>>>(
        x, nn1_W1, nn1_b1, nn1_W2, nn1_b2, nn1_W3, nn1_b3, codebook,
        (const float4*)ygen_id, (const float4*)ygen, (float4*)out,
        h, bin_idx);

    scatter_kernel<<<NBINS, 640, 0, stream>>>(bin_idx, order);

    graph_kernel<<<NBINS, 640, 0, stream>>>(h, order, gcn_W, gcn_b, gcn_n, agg_n);

    nn23_kernel<<<NN / NB, 640, 0, stream>>>(
        gcn_n, agg_n, gc_Wrel, gc_brel, gc_Wroot,
        nn2_W1, nn2_b1, nn2_W2, nn2_b2, nn2_W3, nn2_b3,
        nn3_W1, nn3_b1, nn3_W2, nn3_b2, nn3_W3, nn3_b3,
        out, out + 30000);
}